// Round 2
// baseline (1162.599 us; speedup 1.0000x reference)
//
#include <hip/hip_runtime.h>

// LocalRefinedAttention, round 2: one wave = one patch, fully in-register,
// zero LDS, zero barriers. Layout chaining via C-frag(D) == A-frag(D^T).
//
// B=4, C=64, H=W=192, PS=8, STRIDE=4, PAD=2, NHEADS=4, head_dim=16.
// tok[t][s] = xpad[b, ch=t, patch-spatial s]; out channel = t, spatial = proj idx.

typedef _Float16 f16;
typedef _Float16 f16x4 __attribute__((ext_vector_type(4)));
typedef _Float16 f16x8 __attribute__((ext_vector_type(8)));
typedef float    f32x4 __attribute__((ext_vector_type(4)));

#define NHP 48
#define LPB (NHP * NHP)      // 2304 patches per batch image
#define NPATCH (4 * LPB)     // 9216

#define MFMA32(A, B, C) __builtin_amdgcn_mfma_f32_16x16x32_f16((A), (B), (C), 0, 0, 0)
#define MFMA16(A, B, C) __builtin_amdgcn_mfma_f32_16x16x16f16((A), (B), (C), 0, 0, 0)

static __device__ __forceinline__ f16x4 pack4(f32x4 a) {
    f16x4 r;
    r[0] = (f16)a[0]; r[1] = (f16)a[1]; r[2] = (f16)a[2]; r[3] = (f16)a[3];
    return r;
}

// ---- weights fp32 -> f16 row-major; SCALE*log2(e) folded into Wq ----
__global__ __launch_bounds__(256) void wcvt_kernel(
    const float* __restrict__ wq, const float* __restrict__ wk,
    const float* __restrict__ wv, const float* __restrict__ wp,
    f16* __restrict__ wh)
{
    const int idx = blockIdx.x * 256 + threadIdx.x;   // 0..16383
    const int m = idx >> 12;
    const int r = idx & 4095;
    const float* src = (m == 0) ? wq : (m == 1) ? wk : (m == 2) ? wv : wp;
    const float s = (m == 0) ? 0.36067376022224085f : 1.0f;  // 0.25 * log2(e)
    wh[idx] = (f16)(src[r] * s);
}

// ---- main kernel: 4 waves/block, each wave owns one full patch ----
__global__ __launch_bounds__(256, 3) void patch_attn_kernel(
    const float* __restrict__ x, const f16* __restrict__ wh,
    float* __restrict__ out)
{
    const int tid  = threadIdx.x;
    const int lane = tid & 63;
    const int lr   = lane & 15;
    const int lg   = lane >> 4;

    const int pid = blockIdx.x * 4 + (tid >> 6);
    const int b   = pid / LPB;
    const int rem = pid - b * LPB;
    const int ib  = rem / NHP;
    const int jb  = rem - ib * NHP;
    const int r0  = ib * 4 - 2;
    const int c0  = jb * 4 - 2;

    const f32x4 Z = (f32x4){0.f, 0.f, 0.f, 0.f};

    // ---- X straight into A-frags: lane holds X[t = rt*16+lr][k = kt*32+lg*8+q]
    //      = x[b][ch=rt*16+lr][r0 + kt*4+lg][c0 + q]
    f16x8 Xf[4][2];
    const float* xb = x + (size_t)b * 64 * 192 * 192;
    #pragma unroll
    for (int rt = 0; rt < 4; ++rt) {
        #pragma unroll
        for (int kt = 0; kt < 2; ++kt) {
            const int rr = r0 + kt * 4 + lg;
            f16x8 v;
            #pragma unroll
            for (int q = 0; q < 8; ++q) v[q] = (f16)0.f;
            if (rr >= 0 && rr < 192) {
                const float* src = xb + ((size_t)(rt * 16 + lr) * 192 + rr) * 192 + c0;
                #pragma unroll
                for (int q2 = 0; q2 < 4; ++q2) {
                    const int col = c0 + 2 * q2;          // even -> 8B aligned pair
                    if (col >= 0 && col <= 190) {
                        const float2 t2 = *(const float2*)(src + 2 * q2);
                        v[2 * q2]     = (f16)t2.x;
                        v[2 * q2 + 1] = (f16)t2.y;
                    }
                }
            }
            Xf[rt][kt] = v;
        }
    }

    // ---- per-head: project Q/K/V^T (head slice only), attention, keep O frags
    f16x4 Of[4][4];   // lane holds O[t = rt*16+lr][d = h*16 + lg*4+rg]
    #pragma unroll
    for (int h = 0; h < 4; ++h) {
        const int wrow = (h * 16 + lr) * 64 + lg * 8;
        const f16x8 wq0 = *(const f16x8*)&wh[wrow];
        const f16x8 wq1 = *(const f16x8*)&wh[wrow + 32];
        const f16x8 wk0 = *(const f16x8*)&wh[4096 + wrow];
        const f16x8 wk1 = *(const f16x8*)&wh[4096 + wrow + 32];
        const f16x8 wv0 = *(const f16x8*)&wh[8192 + wrow];
        const f16x8 wv1 = *(const f16x8*)&wh[8192 + wrow + 32];

        f16x4 Qh[4], Kh[4], VTh[4];
        #pragma unroll
        for (int rt = 0; rt < 4; ++rt) {
            f32x4 aq = Z;
            aq = MFMA32(wq0, Xf[rt][0], aq);
            aq = MFMA32(wq1, Xf[rt][1], aq);
            Qh[rt] = pack4(aq);                 // Q[t=lr][d=lg*4+rg] (scaled)
            f32x4 ak = Z;
            ak = MFMA32(wk0, Xf[rt][0], ak);
            ak = MFMA32(wk1, Xf[rt][1], ak);
            Kh[rt] = pack4(ak);                 // K[u=lr][d=lg*4+rg]
            f32x4 av = Z;
            av = MFMA32(Xf[rt][0], wv0, av);
            av = MFMA32(Xf[rt][1], wv1, av);
            VTh[rt] = pack4(av);                // V^T[d=lr][u=lg*4+rg]
        }

        #pragma unroll
        for (int rt = 0; rt < 4; ++rt) {
            // S row block: lane holds S[t=lr][u = ut*16 + lg*4+rg] (log2-domain)
            f32x4 s[4];
            #pragma unroll
            for (int ut = 0; ut < 4; ++ut)
                s[ut] = MFMA16(Kh[ut], Qh[rt], Z);

            float mx = s[0][0];
            #pragma unroll
            for (int ut = 0; ut < 4; ++ut)
                #pragma unroll
                for (int i = 0; i < 4; ++i) mx = fmaxf(mx, s[ut][i]);
            mx = fmaxf(mx, __shfl_xor(mx, 16, 64));
            mx = fmaxf(mx, __shfl_xor(mx, 32, 64));

            float sum = 0.f;
            #pragma unroll
            for (int ut = 0; ut < 4; ++ut)
                #pragma unroll
                for (int i = 0; i < 4; ++i) {
                    const float e = __builtin_amdgcn_exp2f(s[ut][i] - mx);
                    s[ut][i] = e;
                    sum += e;
                }
            sum += __shfl_xor(sum, 16, 64);
            sum += __shfl_xor(sum, 32, 64);
            const float rs = __builtin_amdgcn_rcpf(sum);

            f16x4 pf[4];                        // P[t=lr][u = ut*16 + lg*4+i]
            #pragma unroll
            for (int ut = 0; ut < 4; ++ut)
                #pragma unroll
                for (int i = 0; i < 4; ++i) pf[ut][i] = (f16)(s[ut][i] * rs);

            f32x4 o = Z;
            #pragma unroll
            for (int ut = 0; ut < 4; ++ut)
                o = MFMA16(VTh[ut], pf[ut], o);
            Of[rt][h] = pack4(o);
        }
    }

    // ---- Y = O*Wp^T, scatter with analytic fold-count pre-scale ----
    const float r1 = 1.f / (1.f + 1e-6f);
    const float r2 = 1.f / (2.f + 1e-6f);
    const float r4 = 1.f / (4.f + 1e-6f);
    #pragma unroll
    for (int c = 0; c < 4; ++c) {
        f16x4 wp[4];
        #pragma unroll
        for (int dt = 0; dt < 4; ++dt)
            wp[dt] = *(const f16x4*)&wh[3 * 4096 + (c * 16 + lr) * 64 + dt * 16 + lg * 4];

        // spatial index cs = c*16 + lg*4 + rg -> pi = 2c + (lg>>1) (lane-const), pj = (lg&1)*4 + rg
        const int hh  = r0 + 2 * c + (lg >> 1);
        const bool rok = (hh >= 0 && hh < 192);
        const bool h2  = (hh >= 2 && hh <= 189);
        const int wb  = c0 + (lg & 1) * 4;

        #pragma unroll
        for (int rt = 0; rt < 4; ++rt) {
            f32x4 y = Z;
            #pragma unroll
            for (int dt = 0; dt < 4; ++dt)
                y = MFMA16(wp[dt], Of[rt][dt], y);
            // lane holds Y[t = rt*16+lr][cs = c*16 + lg*4+rg]
            if (rok) {
                const int t = rt * 16 + lr;
                float* op = out + ((size_t)(b * 64 + t) * 192 + hh) * 192;
                #pragma unroll
                for (int rg = 0; rg < 4; ++rg) {
                    const int ww = wb + rg;
                    if (ww >= 0 && ww < 192) {
                        const bool w2 = (ww >= 2 && ww <= 189);
                        const float sc = h2 ? (w2 ? r4 : r2) : (w2 ? r2 : r1);
                        atomicAdd(op + ww, y[rg] * sc);
                    }
                }
            }
        }
    }
}

extern "C" void kernel_launch(void* const* d_in, const int* in_sizes, int n_in,
                              void* d_out, int out_size, void* d_ws, size_t ws_size,
                              hipStream_t stream)
{
    const float* x  = (const float*)d_in[0];
    const float* wq = (const float*)d_in[1];
    const float* wk = (const float*)d_in[2];
    const float* wv = (const float*)d_in[3];
    const float* wp = (const float*)d_in[4];
    float* out = (float*)d_out;
    f16* wh = (f16*)d_ws;   // 32 KiB

    hipMemsetAsync(d_out, 0, (size_t)out_size * sizeof(float), stream);
    wcvt_kernel<<<64, 256, 0, stream>>>(wq, wk, wv, wp, wh);
    patch_attn_kernel<<<NPATCH / 4, 256, 0, stream>>>(x, wh, out);
}

// Round 3
// 347.304 us; speedup vs baseline: 3.3475x; 3.3475x over previous
//
#include <hip/hip_runtime.h>

// LocalRefinedAttention round 3: 4 waves/patch (wave = 16-token tile), one
// barrier, Q in regs, K/V through packed LDS (b64 both sides), no atomics:
// scatter to 4 f16 parity planes in d_ws, then dense coalesced fold pass.
//
// B=4, C=64, H=W=192, PS=8, STRIDE=4, PAD=2, NHEADS=4, head_dim=16.
// token t = channel; feature/spatial s = pi*8+pj; h = 4*ib+pi-2, w = 4*jb+pj-2.
// Parity planes: p = (pi>=4)*2 + (pj>=4); plane[p][b][ch][h][w2=196] at w2=w+2.
// Each (pixel, p) has exactly one writing patch -> no atomics, no memset.

typedef _Float16 f16;
typedef _Float16 f16x4 __attribute__((ext_vector_type(4)));
typedef _Float16 f16x8 __attribute__((ext_vector_type(8)));
typedef float    f32x4 __attribute__((ext_vector_type(4)));

#define NHP 48
#define LPB (NHP * NHP)          // 2304
#define NPATCH (4 * LPB)         // 9216
#define PLELEM (256 * 192 * 196) // f16 elements per parity plane (9,633,792)
#define WS_NEED (32768ull + 4ull * PLELEM * 2ull)

#define MFMA32(A, B, C) __builtin_amdgcn_mfma_f32_16x16x32_f16((A), (B), (C), 0, 0, 0)
#define MFMA16(A, B, C) __builtin_amdgcn_mfma_f32_16x16x16f16((A), (B), (C), 0, 0, 0)

static __device__ __forceinline__ f16x4 pack4(f32x4 a) {
    f16x4 r;
    r[0] = (f16)a[0]; r[1] = (f16)a[1]; r[2] = (f16)a[2]; r[3] = (f16)a[3];
    return r;
}

// ---- weights fp32 -> f16 row-major; SCALE*log2(e) folded into Wq ----
__global__ __launch_bounds__(256) void wcvt_kernel(
    const float* __restrict__ wq, const float* __restrict__ wk,
    const float* __restrict__ wv, const float* __restrict__ wp,
    f16* __restrict__ wh)
{
    const int idx = blockIdx.x * 256 + threadIdx.x;   // 0..16383
    const int m = idx >> 12;
    const int r = idx & 4095;
    const float* src = (m == 0) ? wq : (m == 1) ? wk : (m == 2) ? wv : wp;
    const float s = (m == 0) ? 0.36067376022224085f : 1.0f;  // 0.25 * log2(e)
    wh[idx] = (f16)(src[r] * s);
}

template <bool USE_PLANES>
__global__ __launch_bounds__(256, 4) void patch_attn_kernel(
    const float* __restrict__ x, const f16* __restrict__ wh,
    f16* __restrict__ planes, float* __restrict__ out)
{
    // Packed LDS: Kp[d>>2][key][d&3], Vp[key>>2][d][key&3] -> 8 KB each.
    __shared__ f16 Kp[4096];
    __shared__ f16 Vp[4096];

    const int tid  = threadIdx.x;
    const int wv_  = tid >> 6;
    const int lane = tid & 63;
    const int lr   = lane & 15;
    const int lg   = lane >> 4;

    const int pid = blockIdx.x;
    const int b   = pid / LPB;
    const int rem = pid - b * LPB;
    const int ib  = rem / NHP;
    const int jb  = rem - ib * NHP;
    const int r0  = ib * 4 - 2;
    const int c0  = jb * 4 - 2;

    const f32x4 Z = (f32x4){0.f, 0.f, 0.f, 0.f};

    // ---- X frags for own token tile: lane holds X[t=wv*16+lr][f=kt*32+lg*8+q]
    f16x8 Xf[2];
    {
        const int ch = wv_ * 16 + lr;
        const float* xrow = x + ((size_t)(b * 64 + ch) * 192) * 192;
        #pragma unroll
        for (int kt = 0; kt < 2; ++kt) {
            const int rr = r0 + kt * 4 + lg;
            f16x8 v;
            #pragma unroll
            for (int q = 0; q < 8; ++q) v[q] = (f16)0.f;
            if (rr >= 0 && rr < 192) {
                const float* src = xrow + (size_t)rr * 192 + c0;
                #pragma unroll
                for (int q2 = 0; q2 < 4; ++q2) {
                    const int col = c0 + 2 * q2;      // even -> 8B aligned
                    if (col >= 0 && col <= 190) {
                        const float2 t2 = *(const float2*)(src + 2 * q2);
                        v[2 * q2]     = (f16)t2.x;
                        v[2 * q2 + 1] = (f16)t2.y;
                    }
                }
            }
            Xf[kt] = v;
        }
    }

    // ---- Phase 1: Q (regs), K,V -> packed LDS ----
    f16x4 Qf[4];   // per head: lane holds Q^T[d=h*16+lg*4+rg][q=lr] (scaled,log2)
    {
        #pragma unroll
        for (int h = 0; h < 4; ++h) {
            const int row = (h * 16 + lr) * 64 + lg * 8;
            f32x4 a = Z;
            a = MFMA32(*(const f16x8*)&wh[row],      Xf[0], a);
            a = MFMA32(*(const f16x8*)&wh[row + 32], Xf[1], a);
            Qf[h] = pack4(a);
        }
        const f16* whk = wh + 4096;
        #pragma unroll
        for (int dj = 0; dj < 4; ++dj) {
            const int row = (dj * 16 + lr) * 64 + lg * 8;
            f32x4 a = Z;
            a = MFMA32(*(const f16x8*)&whk[row],      Xf[0], a);
            a = MFMA32(*(const f16x8*)&whk[row + 32], Xf[1], a);
            // C[d=dj*16+lg*4+rg][key=wv*16+lr] -> Kp[(d>>2)=dj*4+lg][key][rg]
            *(f16x4*)&Kp[(((dj * 4 + lg) * 64) + wv_ * 16 + lr) * 4] = pack4(a);
        }
        const f16* whv = wh + 8192;
        #pragma unroll
        for (int dt = 0; dt < 4; ++dt) {
            const int row = (dt * 16 + lr) * 64 + lg * 8;
            f32x4 a = Z;
            a = MFMA32(Xf[0], *(const f16x8*)&whv[row],      a);
            a = MFMA32(Xf[1], *(const f16x8*)&whv[row + 32], a);
            // C[key=wv*16+lg*4+rg][d=dt*16+lr] -> Vp[(key>>2)=wv*4+lg][d][rg]
            *(f16x4*)&Vp[(((wv_ * 4 + lg) * 64) + dt * 16 + lr) * 4] = pack4(a);
        }
    }
    __syncthreads();

    // ---- Phase 2+3: per head, S^T -> softmax -> PV (all in-register) ----
    f16x4 Of[4];   // lane holds O^T[d=h*16+lg*4+rg][q=lr]
    #pragma unroll
    for (int h = 0; h < 4; ++h) {
        f32x4 s[4];
        #pragma unroll
        for (int kt = 0; kt < 4; ++kt) {
            const f16x4 kf = *(const f16x4*)&Kp[(((h * 4 + lg) * 64) + kt * 16 + lr) * 4];
            s[kt] = MFMA16(kf, Qf[h], Z);   // S^T[key=kt*16+lg*4+rg][q=lr] (log2)
        }
        float mx = s[0][0];
        #pragma unroll
        for (int kt = 0; kt < 4; ++kt)
            #pragma unroll
            for (int i = 0; i < 4; ++i) mx = fmaxf(mx, s[kt][i]);
        mx = fmaxf(mx, __shfl_xor(mx, 16, 64));
        mx = fmaxf(mx, __shfl_xor(mx, 32, 64));
        float sum = 0.f;
        #pragma unroll
        for (int kt = 0; kt < 4; ++kt)
            #pragma unroll
            for (int i = 0; i < 4; ++i) {
                const float e = __builtin_amdgcn_exp2f(s[kt][i] - mx);
                s[kt][i] = e;
                sum += e;
            }
        sum += __shfl_xor(sum, 16, 64);
        sum += __shfl_xor(sum, 32, 64);
        const float rs = __builtin_amdgcn_rcpf(sum);

        f16x4 pf[4];   // P[q=lr][key=kt*16+lg*4+i]
        #pragma unroll
        for (int kt = 0; kt < 4; ++kt)
            #pragma unroll
            for (int i = 0; i < 4; ++i) pf[kt][i] = (f16)(s[kt][i] * rs);

        f32x4 o = Z;
        #pragma unroll
        for (int kt = 0; kt < 4; ++kt) {
            const f16x4 vf = *(const f16x4*)&Vp[(((kt * 4 + lg) * 64) + h * 16 + lr) * 4];
            o = MFMA16(vf, pf[kt], o);      // O^T[d][q] accumulate over key tiles
        }
        Of[h] = pack4(o);
    }

    // ---- Phase 4: Y^T = Wp * O^T ; lane holds Y[cs=ct*16+lg*4+rg][q=lr] ----
    const f16* whp = wh + 3 * 4096;
    const int ch  = b * 64 + wv_ * 16 + lr;   // output channel (with batch)
    #pragma unroll
    for (int ct = 0; ct < 4; ++ct) {
        f32x4 y = Z;
        #pragma unroll
        for (int dt = 0; dt < 4; ++dt) {
            const f16x4 wa = *(const f16x4*)&whp[(ct * 16 + lr) * 64 + dt * 16 + lg * 4];
            y = MFMA16(wa, Of[dt], y);
        }
        const int pi  = ct * 2 + (lg >> 1);   // cs = ct*16+lg*4+rg -> pi, pj=(lg&1)*4+rg
        const int pjh = lg & 1;
        const int hh  = r0 + pi;
        if (USE_PLANES) {
            if (hh >= 0 && hh < 192) {
                const int p = (pi >> 2) * 2 + pjh;
                const size_t off = ((size_t)ch * 192 + hh) * 196 + 4 * (jb + pjh);
                *(f16x4*)(planes + (size_t)p * PLELEM + off) = pack4(y);
            }
        } else {
            if (hh >= 0 && hh < 192) {
                const float chc = (hh >= 2 && hh <= 189) ? 2.f : 1.f;
                float* op = out + ((size_t)ch * 192 + hh) * 192;
                #pragma unroll
                for (int rg = 0; rg < 4; ++rg) {
                    const int ww = c0 + pjh * 4 + rg;
                    if (ww >= 0 && ww < 192) {
                        const float cwc = (ww >= 2 && ww <= 189) ? 2.f : 1.f;
                        atomicAdd(op + ww, y[rg] / (chc * cwc + 1e-6f));
                    }
                }
            }
        }
    }
}

// ---- Pass B: dense coalesced fold of the 4 parity planes ----
__global__ __launch_bounds__(256) void fold_kernel(
    const f16* __restrict__ planes, float* __restrict__ out)
{
    const int idx = blockIdx.x * 256 + threadIdx.x;   // 0..9437183
    const int w  = idx % 192;
    const int t  = idx / 192;
    const int h  = t % 192;
    const int bc = t / 192;
    const bool vlh = (h <= 189), vhh = (h >= 2);
    const bool vlw = (w <= 189), vhw = (w >= 2);
    const size_t base = ((size_t)bc * 192 + h) * 196 + (w + 2);
    float s = 0.f;
    if (vlh && vlw) s += (float)planes[0 * (size_t)PLELEM + base];
    if (vlh && vhw) s += (float)planes[1 * (size_t)PLELEM + base];
    if (vhh && vlw) s += (float)planes[2 * (size_t)PLELEM + base];
    if (vhh && vhw) s += (float)planes[3 * (size_t)PLELEM + base];
    const float cnt = (float)(((int)vlh + (int)vhh) * ((int)vlw + (int)vhw));
    out[idx] = s / (cnt + 1e-6f);
}

extern "C" void kernel_launch(void* const* d_in, const int* in_sizes, int n_in,
                              void* d_out, int out_size, void* d_ws, size_t ws_size,
                              hipStream_t stream)
{
    const float* x  = (const float*)d_in[0];
    const float* wq = (const float*)d_in[1];
    const float* wk = (const float*)d_in[2];
    const float* wv = (const float*)d_in[3];
    const float* wp = (const float*)d_in[4];
    float* out = (float*)d_out;
    f16* wh = (f16*)d_ws;

    wcvt_kernel<<<64, 256, 0, stream>>>(wq, wk, wv, wp, wh);

    if (ws_size >= WS_NEED) {
        f16* planes = (f16*)((char*)d_ws + 32768);
        patch_attn_kernel<true><<<NPATCH, 256, 0, stream>>>(x, wh, planes, out);
        fold_kernel<<<36864, 256, 0, stream>>>(planes, out);
    } else {
        hipMemsetAsync(d_out, 0, (size_t)out_size * sizeof(float), stream);
        patch_attn_kernel<false><<<NPATCH, 256, 0, stream>>>(x, wh, nullptr, out);
    }
}

// Round 4
// 267.831 us; speedup vs baseline: 4.3408x; 1.2967x over previous
//
#include <hip/hip_runtime.h>

// LocalRefinedAttention round 4 = round 3 + XCD-bijective block swizzle.
// Round 3 counters: FETCH 578 MB (15x input), WRITE 313 MB (4x useful) because
// neighboring patches (sharing columns + write cache lines) land on different
// XCDs under the default n%8 round-robin. Swizzle pid=(n%8)*1152+n/8 gives
// each XCD a contiguous (b,ib,jb)-ordered patch range: overlap reads hit the
// XCD's own L2 and adjacent 8B plane-stores merge into full lines.
//
// B=4, C=64, H=W=192, PS=8, STRIDE=4, PAD=2, NHEADS=4, head_dim=16.
// token t = channel; feature/spatial s = pi*8+pj; h = 4*ib+pi-2, w = 4*jb+pj-2.
// Parity planes: p = (pi>=4)*2 + (pj>=4); plane[p][b][ch][h][w2=196] at w2=w+2.
// Each (pixel, p) has exactly one writing patch -> no atomics, no memset.

typedef _Float16 f16;
typedef _Float16 f16x4 __attribute__((ext_vector_type(4)));
typedef _Float16 f16x8 __attribute__((ext_vector_type(8)));
typedef float    f32x4 __attribute__((ext_vector_type(4)));

#define NHP 48
#define LPB (NHP * NHP)          // 2304
#define NPATCH (4 * LPB)         // 9216
#define PLELEM (256 * 192 * 196) // f16 elements per parity plane
#define WS_NEED (32768ull + 4ull * PLELEM * 2ull)

#define MFMA32(A, B, C) __builtin_amdgcn_mfma_f32_16x16x32_f16((A), (B), (C), 0, 0, 0)
#define MFMA16(A, B, C) __builtin_amdgcn_mfma_f32_16x16x16f16((A), (B), (C), 0, 0, 0)

static __device__ __forceinline__ f16x4 pack4(f32x4 a) {
    f16x4 r;
    r[0] = (f16)a[0]; r[1] = (f16)a[1]; r[2] = (f16)a[2]; r[3] = (f16)a[3];
    return r;
}

// ---- weights fp32 -> f16 row-major; SCALE*log2(e) folded into Wq ----
__global__ __launch_bounds__(256) void wcvt_kernel(
    const float* __restrict__ wq, const float* __restrict__ wk,
    const float* __restrict__ wv, const float* __restrict__ wp,
    f16* __restrict__ wh)
{
    const int idx = blockIdx.x * 256 + threadIdx.x;   // 0..16383
    const int m = idx >> 12;
    const int r = idx & 4095;
    const float* src = (m == 0) ? wq : (m == 1) ? wk : (m == 2) ? wv : wp;
    const float s = (m == 0) ? 0.36067376022224085f : 1.0f;  // 0.25 * log2(e)
    wh[idx] = (f16)(src[r] * s);
}

template <bool USE_PLANES>
__global__ __launch_bounds__(256, 4) void patch_attn_kernel(
    const float* __restrict__ x, const f16* __restrict__ wh,
    f16* __restrict__ planes, float* __restrict__ out)
{
    // Packed LDS: Kp[d>>2][key][d&3], Vp[key>>2][d][key&3] -> 8 KB each.
    __shared__ f16 Kp[4096];
    __shared__ f16 Vp[4096];

    const int tid  = threadIdx.x;
    const int wv_  = tid >> 6;
    const int lane = tid & 63;
    const int lr   = lane & 15;
    const int lg   = lane >> 4;

    // XCD-bijective swizzle: HW sends block n to XCD n%8; give each XCD a
    // contiguous 1152-patch range so same-XCD neighbors are jb-adjacent.
    const int n   = blockIdx.x;
    const int pid = (n & 7) * (NPATCH / 8) + (n >> 3);
    const int b   = pid / LPB;
    const int rem = pid - b * LPB;
    const int ib  = rem / NHP;
    const int jb  = rem - ib * NHP;
    const int r0  = ib * 4 - 2;
    const int c0  = jb * 4 - 2;

    const f32x4 Z = (f32x4){0.f, 0.f, 0.f, 0.f};

    // ---- X frags for own token tile: lane holds X[t=wv*16+lr][f=kt*32+lg*8+q]
    f16x8 Xf[2];
    {
        const int ch = wv_ * 16 + lr;
        const float* xrow = x + ((size_t)(b * 64 + ch) * 192) * 192;
        #pragma unroll
        for (int kt = 0; kt < 2; ++kt) {
            const int rr = r0 + kt * 4 + lg;
            f16x8 v;
            #pragma unroll
            for (int q = 0; q < 8; ++q) v[q] = (f16)0.f;
            if (rr >= 0 && rr < 192) {
                const float* src = xrow + (size_t)rr * 192 + c0;
                #pragma unroll
                for (int q2 = 0; q2 < 4; ++q2) {
                    const int col = c0 + 2 * q2;      // even -> 8B aligned
                    if (col >= 0 && col <= 190) {
                        const float2 t2 = *(const float2*)(src + 2 * q2);
                        v[2 * q2]     = (f16)t2.x;
                        v[2 * q2 + 1] = (f16)t2.y;
                    }
                }
            }
            Xf[kt] = v;
        }
    }

    // ---- Phase 1: Q (regs), K,V -> packed LDS ----
    f16x4 Qf[4];   // per head: lane holds Q^T[d=h*16+lg*4+rg][q=lr] (scaled,log2)
    {
        #pragma unroll
        for (int h = 0; h < 4; ++h) {
            const int row = (h * 16 + lr) * 64 + lg * 8;
            f32x4 a = Z;
            a = MFMA32(*(const f16x8*)&wh[row],      Xf[0], a);
            a = MFMA32(*(const f16x8*)&wh[row + 32], Xf[1], a);
            Qf[h] = pack4(a);
        }
        const f16* whk = wh + 4096;
        #pragma unroll
        for (int dj = 0; dj < 4; ++dj) {
            const int row = (dj * 16 + lr) * 64 + lg * 8;
            f32x4 a = Z;
            a = MFMA32(*(const f16x8*)&whk[row],      Xf[0], a);
            a = MFMA32(*(const f16x8*)&whk[row + 32], Xf[1], a);
            // C[d=dj*16+lg*4+rg][key=wv*16+lr] -> Kp[(d>>2)=dj*4+lg][key][rg]
            *(f16x4*)&Kp[(((dj * 4 + lg) * 64) + wv_ * 16 + lr) * 4] = pack4(a);
        }
        const f16* whv = wh + 8192;
        #pragma unroll
        for (int dt = 0; dt < 4; ++dt) {
            const int row = (dt * 16 + lr) * 64 + lg * 8;
            f32x4 a = Z;
            a = MFMA32(Xf[0], *(const f16x8*)&whv[row],      a);
            a = MFMA32(Xf[1], *(const f16x8*)&whv[row + 32], a);
            // C[key=wv*16+lg*4+rg][d=dt*16+lr] -> Vp[(key>>2)=wv*4+lg][d][rg]
            *(f16x4*)&Vp[(((wv_ * 4 + lg) * 64) + dt * 16 + lr) * 4] = pack4(a);
        }
    }
    __syncthreads();

    // ---- Phase 2+3: per head, S^T -> softmax -> PV (all in-register) ----
    f16x4 Of[4];   // lane holds O^T[d=h*16+lg*4+rg][q=lr]
    #pragma unroll
    for (int h = 0; h < 4; ++h) {
        f32x4 s[4];
        #pragma unroll
        for (int kt = 0; kt < 4; ++kt) {
            const f16x4 kf = *(const f16x4*)&Kp[(((h * 4 + lg) * 64) + kt * 16 + lr) * 4];
            s[kt] = MFMA16(kf, Qf[h], Z);   // S^T[key=kt*16+lg*4+rg][q=lr] (log2)
        }
        float mx = s[0][0];
        #pragma unroll
        for (int kt = 0; kt < 4; ++kt)
            #pragma unroll
            for (int i = 0; i < 4; ++i) mx = fmaxf(mx, s[kt][i]);
        mx = fmaxf(mx, __shfl_xor(mx, 16, 64));
        mx = fmaxf(mx, __shfl_xor(mx, 32, 64));
        float sum = 0.f;
        #pragma unroll
        for (int kt = 0; kt < 4; ++kt)
            #pragma unroll
            for (int i = 0; i < 4; ++i) {
                const float e = __builtin_amdgcn_exp2f(s[kt][i] - mx);
                s[kt][i] = e;
                sum += e;
            }
        sum += __shfl_xor(sum, 16, 64);
        sum += __shfl_xor(sum, 32, 64);
        const float rs = __builtin_amdgcn_rcpf(sum);

        f16x4 pf[4];   // P[q=lr][key=kt*16+lg*4+i]
        #pragma unroll
        for (int kt = 0; kt < 4; ++kt)
            #pragma unroll
            for (int i = 0; i < 4; ++i) pf[kt][i] = (f16)(s[kt][i] * rs);

        f32x4 o = Z;
        #pragma unroll
        for (int kt = 0; kt < 4; ++kt) {
            const f16x4 vf = *(const f16x4*)&Vp[(((kt * 4 + lg) * 64) + h * 16 + lr) * 4];
            o = MFMA16(vf, pf[kt], o);      // O^T[d][q] accumulate over key tiles
        }
        Of[h] = pack4(o);
    }

    // ---- Phase 4: Y^T = Wp * O^T ; lane holds Y[cs=ct*16+lg*4+rg][q=lr] ----
    const f16* whp = wh + 3 * 4096;
    const int ch  = b * 64 + wv_ * 16 + lr;   // output channel (with batch)
    #pragma unroll
    for (int ct = 0; ct < 4; ++ct) {
        f32x4 y = Z;
        #pragma unroll
        for (int dt = 0; dt < 4; ++dt) {
            const f16x4 wa = *(const f16x4*)&whp[(ct * 16 + lr) * 64 + dt * 16 + lg * 4];
            y = MFMA16(wa, Of[dt], y);
        }
        const int pi  = ct * 2 + (lg >> 1);   // cs = ct*16+lg*4+rg -> pi, pj=(lg&1)*4+rg
        const int pjh = lg & 1;
        const int hh  = r0 + pi;
        if (USE_PLANES) {
            if (hh >= 0 && hh < 192) {
                const int p = (pi >> 2) * 2 + pjh;
                const size_t off = ((size_t)ch * 192 + hh) * 196 + 4 * (jb + pjh);
                *(f16x4*)(planes + (size_t)p * PLELEM + off) = pack4(y);
            }
        } else {
            if (hh >= 0 && hh < 192) {
                const float chc = (hh >= 2 && hh <= 189) ? 2.f : 1.f;
                float* op = out + ((size_t)ch * 192 + hh) * 192;
                #pragma unroll
                for (int rg = 0; rg < 4; ++rg) {
                    const int ww = c0 + pjh * 4 + rg;
                    if (ww >= 0 && ww < 192) {
                        const float cwc = (ww >= 2 && ww <= 189) ? 2.f : 1.f;
                        atomicAdd(op + ww, y[rg] / (chc * cwc + 1e-6f));
                    }
                }
            }
        }
    }
}

// ---- Pass B: dense coalesced fold of the 4 parity planes ----
__global__ __launch_bounds__(256) void fold_kernel(
    const f16* __restrict__ planes, float* __restrict__ out)
{
    const int idx = blockIdx.x * 256 + threadIdx.x;   // 0..9437183
    const int w  = idx % 192;
    const int t  = idx / 192;
    const int h  = t % 192;
    const int bc = t / 192;
    const bool vlh = (h <= 189), vhh = (h >= 2);
    const bool vlw = (w <= 189), vhw = (w >= 2);
    const size_t base = ((size_t)bc * 192 + h) * 196 + (w + 2);
    float s = 0.f;
    if (vlh && vlw) s += (float)planes[0 * (size_t)PLELEM + base];
    if (vlh && vhw) s += (float)planes[1 * (size_t)PLELEM + base];
    if (vhh && vlw) s += (float)planes[2 * (size_t)PLELEM + base];
    if (vhh && vhw) s += (float)planes[3 * (size_t)PLELEM + base];
    const float cnt = (float)(((int)vlh + (int)vhh) * ((int)vlw + (int)vhw));
    out[idx] = s / (cnt + 1e-6f);
}

extern "C" void kernel_launch(void* const* d_in, const int* in_sizes, int n_in,
                              void* d_out, int out_size, void* d_ws, size_t ws_size,
                              hipStream_t stream)
{
    const float* x  = (const float*)d_in[0];
    const float* wq = (const float*)d_in[1];
    const float* wk = (const float*)d_in[2];
    const float* wv = (const float*)d_in[3];
    const float* wp = (const float*)d_in[4];
    float* out = (float*)d_out;
    f16* wh = (f16*)d_ws;

    wcvt_kernel<<<64, 256, 0, stream>>>(wq, wk, wv, wp, wh);

    if (ws_size >= WS_NEED) {
        f16* planes = (f16*)((char*)d_ws + 32768);
        patch_attn_kernel<true><<<NPATCH, 256, 0, stream>>>(x, wh, planes, out);
        fold_kernel<<<36864, 256, 0, stream>>>(planes, out);
    } else {
        hipMemsetAsync(d_out, 0, (size_t)out_size * sizeof(float), stream);
        patch_attn_kernel<false><<<NPATCH, 256, 0, stream>>>(x, wh, nullptr, out);
    }
}

// Round 5
// 209.960 us; speedup vs baseline: 5.5372x; 1.2756x over previous
//
#include <hip/hip_runtime.h>

// LocalRefinedAttention round 5 = round 4 + 2 patches/block + register headroom.
// Round 4 post-mortem: traffic ideal (FETCH 19MB / WRITE 77MB) but all pipes
// idle and VGPR_Count=36 -> compiler register-minimized, serializing every
// weight load into a vmcnt(0) round-trip. Fix: __launch_bounds__(256,3)
// (VGPR cap 168) + 2 patches per block so each weight fragment load feeds two
// patches' MFMAs and the softmax chains interleave pairwise (ILP x2).
//
// B=4, C=64, H=W=192, PS=8, STRIDE=4, PAD=2, NHEADS=4, head_dim=16.
// token t = channel; feature/spatial s = pi*8+pj; h = 4*ib+pi-2, w = 4*jb+pj-2.
// Parity planes: p = (pi>=4)*2 + (pj>=4); plane[p][b][ch][h][w2=196] at w2=w+2.
// Each (pixel, p) has exactly one writing patch -> no atomics, no memset.

typedef _Float16 f16;
typedef _Float16 f16x4 __attribute__((ext_vector_type(4)));
typedef _Float16 f16x8 __attribute__((ext_vector_type(8)));
typedef float    f32x4 __attribute__((ext_vector_type(4)));

#define NHP 48
#define LPB (NHP * NHP)          // 2304
#define NPATCH (4 * LPB)         // 9216
#define NBLK (NPATCH / 2)        // 4608 blocks, 2 patches each
#define PLELEM (256 * 192 * 196) // f16 elements per parity plane
#define WS_NEED (32768ull + 4ull * PLELEM * 2ull)

#define MFMA32(A, B, C) __builtin_amdgcn_mfma_f32_16x16x32_f16((A), (B), (C), 0, 0, 0)
#define MFMA16(A, B, C) __builtin_amdgcn_mfma_f32_16x16x16f16((A), (B), (C), 0, 0, 0)

static __device__ __forceinline__ f16x4 pack4(f32x4 a) {
    f16x4 r;
    r[0] = (f16)a[0]; r[1] = (f16)a[1]; r[2] = (f16)a[2]; r[3] = (f16)a[3];
    return r;
}

// ---- weights fp32 -> f16 row-major; SCALE*log2(e) folded into Wq ----
__global__ __launch_bounds__(256) void wcvt_kernel(
    const float* __restrict__ wq, const float* __restrict__ wk,
    const float* __restrict__ wv, const float* __restrict__ wp,
    f16* __restrict__ wh)
{
    const int idx = blockIdx.x * 256 + threadIdx.x;   // 0..16383
    const int m = idx >> 12;
    const int r = idx & 4095;
    const float* src = (m == 0) ? wq : (m == 1) ? wk : (m == 2) ? wv : wp;
    const float s = (m == 0) ? 0.36067376022224085f : 1.0f;  // 0.25 * log2(e)
    wh[idx] = (f16)(src[r] * s);
}

template <bool USE_PLANES>
__global__ __launch_bounds__(256, 3) void patch_attn_kernel(
    const float* __restrict__ x, const f16* __restrict__ wh,
    f16* __restrict__ planes, float* __restrict__ out)
{
    // Packed LDS per patch: Kp[d>>2][key][d&3], Vp[key>>2][d][key&3] (8 KB each)
    __shared__ f16 Kp[2][4096];
    __shared__ f16 Vp[2][4096];

    const int tid  = threadIdx.x;
    const int wv_  = tid >> 6;
    const int lane = tid & 63;
    const int lr   = lane & 15;
    const int lg   = lane >> 4;

    // XCD-bijective swizzle: each XCD gets a contiguous run of 576 pid-pairs
    // (= 1152 patches, (b,ib,jb)-ordered) -> overlap reads L2-local, 8B plane
    // stores from jb-neighbors merge into full lines.
    const int n    = blockIdx.x;
    const int pid2 = (n & 7) * (NBLK / 8) + (n >> 3);

    int bA[2], jbA[2], r0A[2], c0A[2];
    #pragma unroll
    for (int u = 0; u < 2; ++u) {
        const int pid = pid2 * 2 + u;
        const int b   = pid / LPB;
        const int rem = pid - b * LPB;
        const int ib  = rem / NHP;
        const int jb  = rem - ib * NHP;
        bA[u]  = b;
        jbA[u] = jb;
        r0A[u] = ib * 4 - 2;
        c0A[u] = jb * 4 - 2;
    }

    const f32x4 Z = (f32x4){0.f, 0.f, 0.f, 0.f};

    // ---- X frags: lane holds X[u][t=wv*16+lr][f=kt*32+lg*8+q] ----
    f16x8 Xf[2][2];
    #pragma unroll
    for (int u = 0; u < 2; ++u) {
        const int ch = wv_ * 16 + lr;
        const float* xrow = x + ((size_t)(bA[u] * 64 + ch) * 192) * 192;
        #pragma unroll
        for (int kt = 0; kt < 2; ++kt) {
            const int rr = r0A[u] + kt * 4 + lg;
            f16x8 v;
            #pragma unroll
            for (int q = 0; q < 8; ++q) v[q] = (f16)0.f;
            if (rr >= 0 && rr < 192) {
                const float* src = xrow + (size_t)rr * 192 + c0A[u];
                #pragma unroll
                for (int q2 = 0; q2 < 4; ++q2) {
                    const int col = c0A[u] + 2 * q2;      // even -> 8B aligned
                    if (col >= 0 && col <= 190) {
                        const float2 t2 = *(const float2*)(src + 2 * q2);
                        v[2 * q2]     = (f16)t2.x;
                        v[2 * q2 + 1] = (f16)t2.y;
                    }
                }
            }
            Xf[u][kt] = v;
        }
    }

    // ---- Phase 1: Q (regs), K,V -> packed LDS; weight frags shared by pair ----
    f16x4 Qf[2][4];   // per head: lane holds Q^T[d=h*16+lg*4+rg][q=lr] (scaled,log2)
    {
        #pragma unroll
        for (int h = 0; h < 4; ++h) {
            const int row = (h * 16 + lr) * 64 + lg * 8;
            const f16x8 w0 = *(const f16x8*)&wh[row];
            const f16x8 w1 = *(const f16x8*)&wh[row + 32];
            #pragma unroll
            for (int u = 0; u < 2; ++u) {
                f32x4 a = Z;
                a = MFMA32(w0, Xf[u][0], a);
                a = MFMA32(w1, Xf[u][1], a);
                Qf[u][h] = pack4(a);
            }
        }
        const f16* whk = wh + 4096;
        #pragma unroll
        for (int dj = 0; dj < 4; ++dj) {
            const int row = (dj * 16 + lr) * 64 + lg * 8;
            const f16x8 w0 = *(const f16x8*)&whk[row];
            const f16x8 w1 = *(const f16x8*)&whk[row + 32];
            #pragma unroll
            for (int u = 0; u < 2; ++u) {
                f32x4 a = Z;
                a = MFMA32(w0, Xf[u][0], a);
                a = MFMA32(w1, Xf[u][1], a);
                // C[d=dj*16+lg*4+rg][key=wv*16+lr] -> Kp[(d>>2)][key][d&3]
                *(f16x4*)&Kp[u][(((dj * 4 + lg) * 64) + wv_ * 16 + lr) * 4] = pack4(a);
            }
        }
        const f16* whv = wh + 8192;
        #pragma unroll
        for (int dt = 0; dt < 4; ++dt) {
            const int row = (dt * 16 + lr) * 64 + lg * 8;
            const f16x8 w0 = *(const f16x8*)&whv[row];
            const f16x8 w1 = *(const f16x8*)&whv[row + 32];
            #pragma unroll
            for (int u = 0; u < 2; ++u) {
                f32x4 a = Z;
                a = MFMA32(Xf[u][0], w0, a);
                a = MFMA32(Xf[u][1], w1, a);
                // C[key=wv*16+lg*4+rg][d=dt*16+lr] -> Vp[(key>>2)][d][key&3]
                *(f16x4*)&Vp[u][(((wv_ * 4 + lg) * 64) + dt * 16 + lr) * 4] = pack4(a);
            }
        }
    }
    __syncthreads();

    // ---- Phase 2+3: per head, S^T -> softmax -> PV, pairwise interleaved ----
    f16x4 Of[2][4];   // lane holds O^T[d=h*16+lg*4+rg][q=lr]
    #pragma unroll
    for (int h = 0; h < 4; ++h) {
        f32x4 s[2][4];
        #pragma unroll
        for (int u = 0; u < 2; ++u)
            #pragma unroll
            for (int kt = 0; kt < 4; ++kt) {
                const f16x4 kf = *(const f16x4*)&Kp[u][(((h * 4 + lg) * 64) + kt * 16 + lr) * 4];
                s[u][kt] = MFMA16(kf, Qf[u][h], Z);   // S^T[key][q=lr] (log2 domain)
            }

        float mx[2], sum[2], rs[2];
        #pragma unroll
        for (int u = 0; u < 2; ++u) {
            float m = s[u][0][0];
            #pragma unroll
            for (int kt = 0; kt < 4; ++kt)
                #pragma unroll
                for (int i = 0; i < 4; ++i) m = fmaxf(m, s[u][kt][i]);
            mx[u] = m;
        }
        #pragma unroll
        for (int u = 0; u < 2; ++u) mx[u] = fmaxf(mx[u], __shfl_xor(mx[u], 16, 64));
        #pragma unroll
        for (int u = 0; u < 2; ++u) mx[u] = fmaxf(mx[u], __shfl_xor(mx[u], 32, 64));

        #pragma unroll
        for (int u = 0; u < 2; ++u) {
            float acc = 0.f;
            #pragma unroll
            for (int kt = 0; kt < 4; ++kt)
                #pragma unroll
                for (int i = 0; i < 4; ++i) {
                    const float e = __builtin_amdgcn_exp2f(s[u][kt][i] - mx[u]);
                    s[u][kt][i] = e;
                    acc += e;
                }
            sum[u] = acc;
        }
        #pragma unroll
        for (int u = 0; u < 2; ++u) sum[u] += __shfl_xor(sum[u], 16, 64);
        #pragma unroll
        for (int u = 0; u < 2; ++u) sum[u] += __shfl_xor(sum[u], 32, 64);
        #pragma unroll
        for (int u = 0; u < 2; ++u) rs[u] = __builtin_amdgcn_rcpf(sum[u]);

        #pragma unroll
        for (int u = 0; u < 2; ++u) {
            f16x4 pf[4];   // P[q=lr][key=kt*16+lg*4+i]
            #pragma unroll
            for (int kt = 0; kt < 4; ++kt)
                #pragma unroll
                for (int i = 0; i < 4; ++i) pf[kt][i] = (f16)(s[u][kt][i] * rs[u]);
            f32x4 o = Z;
            #pragma unroll
            for (int kt = 0; kt < 4; ++kt) {
                const f16x4 vf = *(const f16x4*)&Vp[u][(((kt * 4 + lg) * 64) + h * 16 + lr) * 4];
                o = MFMA16(vf, pf[kt], o);      // O^T[d][q] accumulate
            }
            Of[u][h] = pack4(o);
        }
    }

    // ---- Phase 4: Y^T = Wp * O^T ; wp frags shared by the pair ----
    const f16* whp = wh + 3 * 4096;
    #pragma unroll
    for (int ct = 0; ct < 4; ++ct) {
        f16x4 wa[4];
        #pragma unroll
        for (int dt = 0; dt < 4; ++dt)
            wa[dt] = *(const f16x4*)&whp[(ct * 16 + lr) * 64 + dt * 16 + lg * 4];

        const int pi  = ct * 2 + (lg >> 1);   // cs = ct*16+lg*4+rg -> pi, pj=(lg&1)*4+rg
        const int pjh = lg & 1;

        #pragma unroll
        for (int u = 0; u < 2; ++u) {
            f32x4 y = Z;
            #pragma unroll
            for (int dt = 0; dt < 4; ++dt)
                y = MFMA16(wa[dt], Of[u][dt], y);
            // lane holds Y[cs=ct*16+lg*4+rg][q=lr]; token q=lr -> channel
            const int ch = bA[u] * 64 + wv_ * 16 + lr;
            const int hh = r0A[u] + pi;
            if (USE_PLANES) {
                if (hh >= 0 && hh < 192) {
                    const int p = (pi >> 2) * 2 + pjh;
                    const size_t off = ((size_t)ch * 192 + hh) * 196 + 4 * (jbA[u] + pjh);
                    *(f16x4*)(planes + (size_t)p * PLELEM + off) = pack4(y);
                }
            } else {
                if (hh >= 0 && hh < 192) {
                    const float chc = (hh >= 2 && hh <= 189) ? 2.f : 1.f;
                    float* op = out + ((size_t)ch * 192 + hh) * 192;
                    #pragma unroll
                    for (int rg = 0; rg < 4; ++rg) {
                        const int ww = c0A[u] + pjh * 4 + rg;
                        if (ww >= 0 && ww < 192) {
                            const float cwc = (ww >= 2 && ww <= 189) ? 2.f : 1.f;
                            atomicAdd(op + ww, y[rg] / (chc * cwc + 1e-6f));
                        }
                    }
                }
            }
        }
    }
}

// ---- Pass B: dense coalesced fold of the 4 parity planes ----
__global__ __launch_bounds__(256) void fold_kernel(
    const f16* __restrict__ planes, float* __restrict__ out)
{
    const int idx = blockIdx.x * 256 + threadIdx.x;   // 0..9437183
    const int w  = idx % 192;
    const int t  = idx / 192;
    const int h  = t % 192;
    const int bc = t / 192;
    const bool vlh = (h <= 189), vhh = (h >= 2);
    const bool vlw = (w <= 189), vhw = (w >= 2);
    const size_t base = ((size_t)bc * 192 + h) * 196 + (w + 2);
    float s = 0.f;
    if (vlh && vlw) s += (float)planes[0 * (size_t)PLELEM + base];
    if (vlh && vhw) s += (float)planes[1 * (size_t)PLELEM + base];
    if (vhh && vlw) s += (float)planes[2 * (size_t)PLELEM + base];
    if (vhh && vhw) s += (float)planes[3 * (size_t)PLELEM + base];
    const float cnt = (float)(((int)vlh + (int)vhh) * ((int)vlw + (int)vhw));
    out[idx] = s / (cnt + 1e-6f);
}

extern "C" void kernel_launch(void* const* d_in, const int* in_sizes, int n_in,
                              void* d_out, int out_size, void* d_ws, size_t ws_size,
                              hipStream_t stream)
{
    const float* x  = (const float*)d_in[0];
    const float* wq = (const float*)d_in[1];
    const float* wk = (const float*)d_in[2];
    const float* wv = (const float*)d_in[3];
    const float* wp = (const float*)d_in[4];
    float* out = (float*)d_out;
    f16* wh = (f16*)d_ws;

    wcvt_kernel<<<64, 256, 0, stream>>>(wq, wk, wv, wp, wh);

    if (ws_size >= WS_NEED) {
        f16* planes = (f16*)((char*)d_ws + 32768);
        patch_attn_kernel<true><<<NBLK, 256, 0, stream>>>(x, wh, planes, out);
        fold_kernel<<<36864, 256, 0, stream>>>(planes, out);
    } else {
        hipMemsetAsync(d_out, 0, (size_t)out_size * sizeof(float), stream);
        patch_attn_kernel<false><<<NBLK, 256, 0, stream>>>(x, wh, nullptr, out);
    }
}

// Round 6
// 189.620 us; speedup vs baseline: 6.1312x; 1.1073x over previous
//
#include <hip/hip_runtime.h>

// LocalRefinedAttention round 6 = round 5 + forced load clustering.
// Round 5 post-mortem: VGPR stayed at 52 despite the cap -> compiler still
// emits load->wait->use serial chains (12 weight-fragment L2 round-trips per
// wave in phase 1). Fix: issue ALL global loads (X + 24 weight frags) in one
// cluster pinned by sched_barrier(0); clamped-address + select-zero X loads
// (no divergent branches fragmenting the cluster); per-head ds_read batches
// in phase 2; batched Wp frags in phase 4.
//
// B=4, C=64, H=W=192, PS=8, STRIDE=4, PAD=2, NHEADS=4, head_dim=16.
// token t = channel; feature/spatial s = pi*8+pj; h = 4*ib+pi-2, w = 4*jb+pj-2.
// Parity planes: p = (pi>=4)*2 + (pj>=4); plane[p][b][ch][h][w2=196] at w2=w+2.
// Each (pixel, p) has exactly one writing patch -> no atomics, no memset.

typedef _Float16 f16;
typedef _Float16 f16x4 __attribute__((ext_vector_type(4)));
typedef _Float16 f16x8 __attribute__((ext_vector_type(8)));
typedef float    f32x4 __attribute__((ext_vector_type(4)));

#define NHP 48
#define LPB (NHP * NHP)          // 2304
#define NPATCH (4 * LPB)         // 9216
#define NBLK (NPATCH / 2)        // 4608 blocks, 2 patches each
#define PLELEM (256 * 192 * 196) // f16 elements per parity plane
#define WS_NEED (32768ull + 4ull * PLELEM * 2ull)

#define MFMA32(A, B, C) __builtin_amdgcn_mfma_f32_16x16x32_f16((A), (B), (C), 0, 0, 0)
#define MFMA16(A, B, C) __builtin_amdgcn_mfma_f32_16x16x16f16((A), (B), (C), 0, 0, 0)

static __device__ __forceinline__ f16x4 pack4(f32x4 a) {
    f16x4 r;
    r[0] = (f16)a[0]; r[1] = (f16)a[1]; r[2] = (f16)a[2]; r[3] = (f16)a[3];
    return r;
}

// ---- weights fp32 -> f16 row-major; SCALE*log2(e) folded into Wq ----
__global__ __launch_bounds__(256) void wcvt_kernel(
    const float* __restrict__ wq, const float* __restrict__ wk,
    const float* __restrict__ wv, const float* __restrict__ wp,
    f16* __restrict__ wh)
{
    const int idx = blockIdx.x * 256 + threadIdx.x;   // 0..16383
    const int m = idx >> 12;
    const int r = idx & 4095;
    const float* src = (m == 0) ? wq : (m == 1) ? wk : (m == 2) ? wv : wp;
    const float s = (m == 0) ? 0.36067376022224085f : 1.0f;  // 0.25 * log2(e)
    wh[idx] = (f16)(src[r] * s);
}

template <bool USE_PLANES>
__global__ __launch_bounds__(256, 3) void patch_attn_kernel(
    const float* __restrict__ x, const f16* __restrict__ wh,
    f16* __restrict__ planes, float* __restrict__ out)
{
    // Packed LDS per patch: Kp[d>>2][key][d&3], Vp[key>>2][d][key&3] (8 KB each)
    __shared__ f16 Kp[2][4096];
    __shared__ f16 Vp[2][4096];

    const int tid  = threadIdx.x;
    const int wv_  = tid >> 6;
    const int lane = tid & 63;
    const int lr   = lane & 15;
    const int lg   = lane >> 4;

    // XCD-bijective swizzle: each XCD gets a contiguous run of 576 pid-pairs
    // (= 1152 patches, (b,ib,jb)-ordered) -> overlap reads L2-local, 8B plane
    // stores from jb-neighbors merge into full lines.
    const int n    = blockIdx.x;
    const int pid2 = (n & 7) * (NBLK / 8) + (n >> 3);

    int bA[2], jbA[2], r0A[2], c0A[2];
    #pragma unroll
    for (int u = 0; u < 2; ++u) {
        const int pid = pid2 * 2 + u;
        const int b   = pid / LPB;
        const int rem = pid - b * LPB;
        const int ib  = rem / NHP;
        const int jb  = rem - ib * NHP;
        bA[u]  = b;
        jbA[u] = jb;
        r0A[u] = ib * 4 - 2;
        c0A[u] = jb * 4 - 2;
    }

    const f32x4 Z = (f32x4){0.f, 0.f, 0.f, 0.f};

    // ================= Cluster 1: issue ALL global loads =================
    // X raw loads, clamped addresses (no divergent branches around loads).
    float2 xr[2][2][4];
    bool   rok[2][2];
    #pragma unroll
    for (int u = 0; u < 2; ++u) {
        const int ch = wv_ * 16 + lr;
        const float* xb = x + ((size_t)(bA[u] * 64 + ch) * 192) * 192;
        #pragma unroll
        for (int kt = 0; kt < 2; ++kt) {
            const int rr = r0A[u] + kt * 4 + lg;
            rok[u][kt] = (rr >= 0) && (rr < 192);
            const int rc = rok[u][kt] ? rr : 0;
            const float* src = xb + (size_t)rc * 192;
            #pragma unroll
            for (int q2 = 0; q2 < 4; ++q2) {
                int col = c0A[u] + 2 * q2;
                col = (col < 0) ? 0 : ((col > 190) ? 190 : col);
                xr[u][kt][q2] = *(const float2*)(src + col);
            }
        }
    }
    // All 24 weight fragments (Wq, Wk, Wv).
    f16x8 wqf[4][2], wkf[4][2], wvf[4][2];
    #pragma unroll
    for (int h = 0; h < 4; ++h) {
        const int row = (h * 16 + lr) * 64 + lg * 8;
        wqf[h][0] = *(const f16x8*)&wh[row];
        wqf[h][1] = *(const f16x8*)&wh[row + 32];
        wkf[h][0] = *(const f16x8*)&wh[4096 + row];
        wkf[h][1] = *(const f16x8*)&wh[4096 + row + 32];
        wvf[h][0] = *(const f16x8*)&wh[8192 + row];
        wvf[h][1] = *(const f16x8*)&wh[8192 + row + 32];
    }
    __builtin_amdgcn_sched_barrier(0);   // loads above, compute below

    // ---- convert X to f16 frags with validity masks ----
    f16x8 Xf[2][2];   // lane holds X[u][t=wv*16+lr][f=kt*32+lg*8+q]
    #pragma unroll
    for (int u = 0; u < 2; ++u)
        #pragma unroll
        for (int kt = 0; kt < 2; ++kt) {
            f16x8 v;
            #pragma unroll
            for (int q2 = 0; q2 < 4; ++q2) {
                const int col = c0A[u] + 2 * q2;
                const bool ok = rok[u][kt] && (col >= 0) && (col <= 190);
                v[2 * q2]     = ok ? (f16)xr[u][kt][q2].x : (f16)0.f;
                v[2 * q2 + 1] = ok ? (f16)xr[u][kt][q2].y : (f16)0.f;
            }
            Xf[u][kt] = v;
        }

    // ---- Phase 1: Q (regs), K,V -> packed LDS ----
    f16x4 Qf[2][4];   // per head: lane holds Q^T[d=h*16+lg*4+rg][q=lr] (scaled,log2)
    #pragma unroll
    for (int h = 0; h < 4; ++h)
        #pragma unroll
        for (int u = 0; u < 2; ++u) {
            f32x4 a = Z;
            a = MFMA32(wqf[h][0], Xf[u][0], a);
            a = MFMA32(wqf[h][1], Xf[u][1], a);
            Qf[u][h] = pack4(a);
        }
    #pragma unroll
    for (int dj = 0; dj < 4; ++dj)
        #pragma unroll
        for (int u = 0; u < 2; ++u) {
            f32x4 a = Z;
            a = MFMA32(wkf[dj][0], Xf[u][0], a);
            a = MFMA32(wkf[dj][1], Xf[u][1], a);
            // C[d=dj*16+lg*4+rg][key=wv*16+lr] -> Kp[(d>>2)][key][d&3]
            *(f16x4*)&Kp[u][(((dj * 4 + lg) * 64) + wv_ * 16 + lr) * 4] = pack4(a);
        }
    #pragma unroll
    for (int dt = 0; dt < 4; ++dt)
        #pragma unroll
        for (int u = 0; u < 2; ++u) {
            f32x4 a = Z;
            a = MFMA32(Xf[u][0], wvf[dt][0], a);
            a = MFMA32(Xf[u][1], wvf[dt][1], a);
            // C[key=wv*16+lg*4+rg][d=dt*16+lr] -> Vp[(key>>2)][d][key&3]
            *(f16x4*)&Vp[u][(((wv_ * 4 + lg) * 64) + dt * 16 + lr) * 4] = pack4(a);
        }
    __syncthreads();

    // ---- Phase 2+3: per head, S^T -> softmax -> PV, pairwise interleaved ----
    f16x4 Of[2][4];   // lane holds O^T[d=h*16+lg*4+rg][q=lr]
    #pragma unroll
    for (int h = 0; h < 4; ++h) {
        // hoisted ds_read batch: all K and V frags this head needs (16 b64)
        f16x4 kf[2][4], vfr[2][4];
        #pragma unroll
        for (int u = 0; u < 2; ++u)
            #pragma unroll
            for (int kt = 0; kt < 4; ++kt) {
                kf[u][kt]  = *(const f16x4*)&Kp[u][(((h * 4 + lg) * 64) + kt * 16 + lr) * 4];
                vfr[u][kt] = *(const f16x4*)&Vp[u][(((kt * 4 + lg) * 64) + h * 16 + lr) * 4];
            }

        f32x4 s[2][4];
        #pragma unroll
        for (int u = 0; u < 2; ++u)
            #pragma unroll
            for (int kt = 0; kt < 4; ++kt)
                s[u][kt] = MFMA16(kf[u][kt], Qf[u][h], Z);   // S^T[key][q=lr] (log2)

        float mx[2], sum[2], rs[2];
        #pragma unroll
        for (int u = 0; u < 2; ++u) {
            float m = s[u][0][0];
            #pragma unroll
            for (int kt = 0; kt < 4; ++kt)
                #pragma unroll
                for (int i = 0; i < 4; ++i) m = fmaxf(m, s[u][kt][i]);
            mx[u] = m;
        }
        #pragma unroll
        for (int u = 0; u < 2; ++u) mx[u] = fmaxf(mx[u], __shfl_xor(mx[u], 16, 64));
        #pragma unroll
        for (int u = 0; u < 2; ++u) mx[u] = fmaxf(mx[u], __shfl_xor(mx[u], 32, 64));

        #pragma unroll
        for (int u = 0; u < 2; ++u) {
            float acc = 0.f;
            #pragma unroll
            for (int kt = 0; kt < 4; ++kt)
                #pragma unroll
                for (int i = 0; i < 4; ++i) {
                    const float e = __builtin_amdgcn_exp2f(s[u][kt][i] - mx[u]);
                    s[u][kt][i] = e;
                    acc += e;
                }
            sum[u] = acc;
        }
        #pragma unroll
        for (int u = 0; u < 2; ++u) sum[u] += __shfl_xor(sum[u], 16, 64);
        #pragma unroll
        for (int u = 0; u < 2; ++u) sum[u] += __shfl_xor(sum[u], 32, 64);
        #pragma unroll
        for (int u = 0; u < 2; ++u) rs[u] = __builtin_amdgcn_rcpf(sum[u]);

        #pragma unroll
        for (int u = 0; u < 2; ++u) {
            f16x4 pf[4];   // P[q=lr][key=kt*16+lg*4+i]
            #pragma unroll
            for (int kt = 0; kt < 4; ++kt)
                #pragma unroll
                for (int i = 0; i < 4; ++i) pf[kt][i] = (f16)(s[u][kt][i] * rs[u]);
            f32x4 o = Z;
            #pragma unroll
            for (int kt = 0; kt < 4; ++kt)
                o = MFMA16(vfr[u][kt], pf[kt], o);      // O^T[d][q] accumulate
            Of[u][h] = pack4(o);
        }
    }

    // ---- Phase 4: Y^T = Wp * O^T ; all 16 Wp frags batched ----
    const f16* whp = wh + 3 * 4096;
    f16x4 wa[4][4];
    #pragma unroll
    for (int ct = 0; ct < 4; ++ct)
        #pragma unroll
        for (int dt = 0; dt < 4; ++dt)
            wa[ct][dt] = *(const f16x4*)&whp[(ct * 16 + lr) * 64 + dt * 16 + lg * 4];

    #pragma unroll
    for (int ct = 0; ct < 4; ++ct) {
        const int pi  = ct * 2 + (lg >> 1);   // cs = ct*16+lg*4+rg -> pi, pj=(lg&1)*4+rg
        const int pjh = lg & 1;

        #pragma unroll
        for (int u = 0; u < 2; ++u) {
            f32x4 y = Z;
            #pragma unroll
            for (int dt = 0; dt < 4; ++dt)
                y = MFMA16(wa[ct][dt], Of[u][dt], y);
            // lane holds Y[cs=ct*16+lg*4+rg][q=lr]; token q=lr -> channel
            const int ch = bA[u] * 64 + wv_ * 16 + lr;
            const int hh = r0A[u] + pi;
            if (USE_PLANES) {
                if (hh >= 0 && hh < 192) {
                    const int p = (pi >> 2) * 2 + pjh;
                    const size_t off = ((size_t)ch * 192 + hh) * 196 + 4 * (jbA[u] + pjh);
                    *(f16x4*)(planes + (size_t)p * PLELEM + off) = pack4(y);
                }
            } else {
                if (hh >= 0 && hh < 192) {
                    const float chc = (hh >= 2 && hh <= 189) ? 2.f : 1.f;
                    float* op = out + ((size_t)ch * 192 + hh) * 192;
                    #pragma unroll
                    for (int rg = 0; rg < 4; ++rg) {
                        const int ww = c0A[u] + pjh * 4 + rg;
                        if (ww >= 0 && ww < 192) {
                            const float cwc = (ww >= 2 && ww <= 189) ? 2.f : 1.f;
                            atomicAdd(op + ww, y[rg] / (chc * cwc + 1e-6f));
                        }
                    }
                }
            }
        }
    }
}

// ---- Pass B: dense coalesced fold of the 4 parity planes ----
__global__ __launch_bounds__(256) void fold_kernel(
    const f16* __restrict__ planes, float* __restrict__ out)
{
    const int idx = blockIdx.x * 256 + threadIdx.x;   // 0..9437183
    const int w  = idx % 192;
    const int t  = idx / 192;
    const int h  = t % 192;
    const int bc = t / 192;
    const bool vlh = (h <= 189), vhh = (h >= 2);
    const bool vlw = (w <= 189), vhw = (w >= 2);
    const size_t base = ((size_t)bc * 192 + h) * 196 + (w + 2);
    float s = 0.f;
    if (vlh && vlw) s += (float)planes[0 * (size_t)PLELEM + base];
    if (vlh && vhw) s += (float)planes[1 * (size_t)PLELEM + base];
    if (vhh && vlw) s += (float)planes[2 * (size_t)PLELEM + base];
    if (vhh && vhw) s += (float)planes[3 * (size_t)PLELEM + base];
    const float cnt = (float)(((int)vlh + (int)vhh) * ((int)vlw + (int)vhw));
    out[idx] = s / (cnt + 1e-6f);
}

extern "C" void kernel_launch(void* const* d_in, const int* in_sizes, int n_in,
                              void* d_out, int out_size, void* d_ws, size_t ws_size,
                              hipStream_t stream)
{
    const float* x  = (const float*)d_in[0];
    const float* wq = (const float*)d_in[1];
    const float* wk = (const float*)d_in[2];
    const float* wv = (const float*)d_in[3];
    const float* wp = (const float*)d_in[4];
    float* out = (float*)d_out;
    f16* wh = (f16*)d_ws;

    wcvt_kernel<<<64, 256, 0, stream>>>(wq, wk, wv, wp, wh);

    if (ws_size >= WS_NEED) {
        f16* planes = (f16*)((char*)d_ws + 32768);
        patch_attn_kernel<true><<<NBLK, 256, 0, stream>>>(x, wh, planes, out);
        fold_kernel<<<36864, 256, 0, stream>>>(planes, out);
    } else {
        hipMemsetAsync(d_out, 0, (size_t)out_size * sizeof(float), stream);
        patch_attn_kernel<false><<<NBLK, 256, 0, stream>>>(x, wh, nullptr, out);
    }
}